// Round 8
// baseline (1014.592 us; speedup 1.0000x reference)
//
#include <hip/hip_runtime.h>

// Problem constants (fixed by setup_inputs)
#define BB 32
#define CC 3
#define HH 257
#define WW 257
#define MASK 17
#define STRIDE 4
#define NWIN 61           // (257-17)/4+1

constexpr int WIN_ELEMS = MASK * MASK;               // 289
constexpr int ROW_ELEMS = NWIN * WIN_ELEMS;          // 17629 contiguous sw elems per (b,c,i)
constexpr long long SW_SIZE = (long long)BB * CC * NWIN * NWIN * WIN_ELEMS; // 103,235,424
constexpr long long S_SIZE  = (long long)BB * 4 * CC * NWIN * NWIN;         // 1,428,864
constexpr int NN2 = NWIN * NWIN;                     // 3721
constexpr int NBLK = BB * CC * NWIN;                 // 5856 = 8 * 732 (divisible by 8 XCDs)

typedef float vf4 __attribute__((ext_vector_type(4)));

// ROUND-8 structural ablation: NO LDS. The per-block x-band is 17.4 KB ->
// fits L1 (32 KB), shared with neighbor blocks in L2 via the XCD remap.
// Removes: staging loop, __syncthreads, bank swizzle. Reads become L1/L2
// hits; waves desync freely (smoother store stream). Plain stores (r7 A/B:
// nontemporal cost +33 us).

// Per-element compute straight from the global x-band.
// j,u,v derived independently per element (ILP; r6's dependent walker regressed).
static __device__ __forceinline__ void compute_elem_g(
        const float* __restrict__ xw, int o, float& sv, float& qv) {
    int j = o / WIN_ELEMS;            // const-div -> magic mul
    int r = o - j * WIN_ELEMS;
    int u = r / MASK;
    int v = r - u * MASK;
    float xv = xw[u * WW + j * STRIDE + v];
    // digitize(x, linspace(0,1,65)) - 1 == clamp(floor(64*x), -1, 64); exact fp32
    int qi = (int)floorf(xv * 64.0f);
    qi = qi < -1 ? -1 : (qi > 64 ? 64 : qi);
    sv = xv;
    qv = (float)qi;
}

__global__ __launch_bounds__(256) void leafnet_kernel(
        const float* __restrict__ x,
        float* __restrict__ sw_out,
        float* __restrict__ s_out,
        float* __restrict__ q_out) {
    // XCD-contiguous block remap (5856 = 8*732 -> clean bijection): neighbor
    // i-blocks (13/17 shared input rows) land on the same per-XCD L2.
    const int hw = blockIdx.x;
    const int bid = (hw & 7) * (NBLK / 8) + (hw >> 3);
    const int i = bid % NWIN;
    const int c = (bid / NWIN) % CC;
    const int b = bid / (NWIN * CC);
    const int tid = threadIdx.x;

    // Base of this block's 17-row x band (contiguous 17*257 floats).
    const float* xw = x + ((size_t)(b * CC + c) * HH + (size_t)i * STRIDE) * WW;

    // ---- sw + q: contiguous span [obase, obase+17629) per block ----
    const size_t obase = (size_t)bid * ROW_ELEMS;
    const size_t gend  = obase + ROW_ELEMS;
    const size_t g0    = (obase + 3) & ~(size_t)3;   // first 16B-aligned element
    const size_t gbe   = gend & ~(size_t)3;          // end of aligned body
    const int head  = (int)(g0 - obase);             // 0..3
    const int tailn = (int)(gend - gbe);             // 0..3
    const int body  = (int)((gbe - g0) >> 2);        // float4 chunks (~4407)

    // scalar head + tail (<= 6 elements total)
    if (tid < 8) {
        int o = -1;
        if (tid < head) o = tid;
        else if (tid - head < tailn) o = (int)(gbe - obase) + (tid - head);
        if (o >= 0) {
            float sv, qv;
            compute_elem_g(xw, o, sv, qv);
            sw_out[obase + o] = sv;
            q_out[obase + o] = qv;
        }
    }

    // vectorized body: one float4 per thread per iteration; per-element
    // address math fully independent (ILP). Reads hit L1 after first touch.
    for (int k = tid; k < body; k += 256) {
        size_t g = g0 + ((size_t)k << 2);
        int o = (int)(g - obase);
        float s0, s1, s2, s3, q0, q1, q2, q3;
        compute_elem_g(xw, o + 0, s0, q0);
        compute_elem_g(xw, o + 1, s1, q1);
        compute_elem_g(xw, o + 2, s2, q2);
        compute_elem_g(xw, o + 3, s3, q3);
        vf4 sv = {s0, s1, s2, s3};
        vf4 qv = {q0, q1, q2, q3};
        *reinterpret_cast<vf4*>(sw_out + g) = sv;
        *reinterpret_cast<vf4*>(q_out + g)  = qv;
    }

    // ---- stats: quad-of-lanes per window, reading the (now L1-warm) band ----
    const int lane = tid & 63;
    const int wave = tid >> 6;
    const int j = (lane >> 2) + (wave << 4);   // 0..63; valid if < 61
    const int q = lane & 3;

    float sum = 0.0f, sumsq = 0.0f, mx = -1e30f, mn = 1e30f;
    if (j < NWIN) {
        const int e0 = 72 * q;
        const int lim = (q == 3) ? 73 : 72;    // 289 = 72*4 + 1
        const int jbase = j * STRIDE;
        for (int s = 0; s < lim; ++s) {
            int e = e0 + s;
            int u = e / MASK;                  // const-div
            int v = e - u * MASK;
            float xv = xw[u * WW + jbase + v];
            // shifted accumulation: var is shift-invariant; better conditioning.
            float xs = xv - 0.5f;
            sum += xs;
            sumsq += xs * xs;
            mx = fmaxf(mx, xv);
            mn = fminf(mn, xv);
        }
    }
    sum   += __shfl_xor(sum, 1, 64);
    sumsq += __shfl_xor(sumsq, 1, 64);
    mx = fmaxf(mx, __shfl_xor(mx, 1, 64));
    mn = fminf(mn, __shfl_xor(mn, 1, 64));
    sum   += __shfl_xor(sum, 2, 64);
    sumsq += __shfl_xor(sumsq, 2, 64);
    mx = fmaxf(mx, __shfl_xor(mx, 2, 64));
    mn = fminf(mn, __shfl_xor(mn, 2, 64));

    if (q == 0 && j < NWIN) {
        const float inv_n = 1.0f / (float)WIN_ELEMS;
        float ms = sum * inv_n;               // E[x] - 0.5
        float mean = 0.5f + ms;
        float var = fmaxf(sumsq * inv_n - ms * ms, 0.0f); // population std
        float sd = sqrtf(var);
        const float inv_std = 4.0f;  // 1 / G_STD
        size_t sb = (size_t)b * 12 * NN2 + (size_t)c * NN2 + (size_t)i * NWIN + j;
        s_out[sb + 0 * (size_t)CC * NN2] = (mx - 0.5f) * inv_std;
        s_out[sb + 1 * (size_t)CC * NN2] = sd * inv_std;
        s_out[sb + 2 * (size_t)CC * NN2] = (mx - mean) * inv_std;
        s_out[sb + 3 * (size_t)CC * NN2] = (mean - mn) * inv_std;
    }
}

extern "C" void kernel_launch(void* const* d_in, const int* in_sizes, int n_in,
                              void* d_out, int out_size, void* d_ws, size_t ws_size,
                              hipStream_t stream) {
    const float* x = (const float*)d_in[0];
    // d_in[1] = bins (linspace(0,1,65)) — semantics hardcoded (exact, see kernel)
    float* out = (float*)d_out;
    float* sw_out = out;
    float* s_out  = out + SW_SIZE;
    float* q_out  = out + SW_SIZE + S_SIZE;

    leafnet_kernel<<<NBLK, 256, 0, stream>>>(x, sw_out, s_out, q_out);
}

// Round 9
// 858.025 us; speedup vs baseline: 1.1825x; 1.1825x over previous
//
#include <hip/hip_runtime.h>

// Problem constants (fixed by setup_inputs)
#define BB 32
#define CC 3
#define HH 257
#define WW 257
#define MASK 17
#define STRIDE 4
#define NWIN 61           // (257-17)/4+1

constexpr int WIN_ELEMS = MASK * MASK;               // 289
constexpr int ROW_ELEMS = NWIN * WIN_ELEMS;          // 17629 contiguous sw elems per (b,c,i)
constexpr int BAND = MASK * WW;                      // 4369 contiguous x floats per block
constexpr long long SW_SIZE = (long long)BB * CC * NWIN * NWIN * WIN_ELEMS; // 103,235,424
constexpr long long S_SIZE  = (long long)BB * 4 * CC * NWIN * NWIN;         // 1,428,864
constexpr int NN2 = NWIN * NWIN;                     // 3721
constexpr int NBLK = BB * CC * NWIN;                 // 5856 = 8 * 732 (divisible by 8 XCDs)

typedef float vf4 __attribute__((ext_vector_type(4)));

// XOR bank swizzle: inject word bits [6:5] into bits [1:0].
// Main-loop lane-to-lane stride is +4 words (each thread owns 4 consecutive
// elements) -> banks {W, W+4..W+28} = 8-way conflict. Bits [6:5] flip every
// 8 lanes, so the XOR spreads 32 lanes over all 32 banks -> ~2-way (free).
// Pitch is now 257 (= WW): LDS band is congruent to the contiguous global
// band, enabling float4 staging loads. Only word 4368 sits in a partial
// 4-group; its XOR constant is (4368>>5)&3 == 0 -> identity, in-bounds.
static __device__ __forceinline__ int swz(int w) {
    return w ^ ((w >> 5) & 3);
}

static __device__ __forceinline__ void compute_elem(
        const float* __restrict__ lds, int o, float& sv, float& qv) {
    int j = o / WIN_ELEMS;            // const-div -> magic mul (independent per elem: ILP)
    int r = o - j * WIN_ELEMS;
    int u = r / MASK;
    int v = r - u * MASK;
    float xv = lds[swz(u * WW + j * STRIDE + v)];
    // digitize(x, linspace(0,1,65)) - 1 == clamp(floor(64*x), -1, 64); exact fp32
    int qi = (int)floorf(xv * 64.0f);
    qi = qi < -1 ? -1 : (qi > 64 ? 64 : qi);
    sv = xv;
    qv = (float)qi;
}

__global__ __launch_bounds__(256) void leafnet_kernel(
        const float* __restrict__ x,
        float* __restrict__ sw_out,
        float* __restrict__ s_out,
        float* __restrict__ q_out) {
    __shared__ float lds[BAND + 3];      // 4369 (+pad) floats = 17.49 KB, pitch 257

    // XCD-contiguous block remap (5856 = 8*732 -> clean bijection): neighbor
    // i-blocks (13/17 shared input rows) land on the same per-XCD L2.
    const int hw = blockIdx.x;
    const int bid = (hw & 7) * (NBLK / 8) + (hw >> 3);
    const int i = bid % NWIN;
    const int c = (bid / NWIN) % CC;
    const int b = bid / (NWIN * CC);
    const int tid = threadIdx.x;

    // ---- staging: float4 loads over the contiguous 4369-float band ----
    const size_t bandbase = ((size_t)(b * CC + c) * HH + (size_t)i * STRIDE) * WW;
    const float* xw = x + bandbase;
    const int mis  = (int)(bandbase & 3);          // base float index mod 4
    const int hcnt = (4 - mis) & 3;                // head words to align
    const int nb4  = (BAND - hcnt) >> 2;           // aligned float4 count (~1092)
    const int tcnt = (BAND - hcnt) & 3;            // tail words

    // head + tail (<= 6 words total)
    if (tid < 8) {
        int w = -1;
        if (tid < hcnt) w = tid;
        else if (tid - hcnt < tcnt) w = hcnt + (nb4 << 2) + (tid - hcnt);
        if (w >= 0) lds[swz(w)] = xw[w];
    }
    // body: one aligned global float4 -> 4 swizzled scalar ds_writes
    // (lane stride 4 words -> conflict-free post-swizzle, same as main reads)
    for (int k = tid; k < nb4; k += 256) {
        int w = hcnt + (k << 2);
        vf4 vv = *reinterpret_cast<const vf4*>(xw + w);
        lds[swz(w + 0)] = vv[0];
        lds[swz(w + 1)] = vv[1];
        lds[swz(w + 2)] = vv[2];
        lds[swz(w + 3)] = vv[3];
    }
    __syncthreads();

    // ---- sw + q: contiguous span [obase, obase+17629) per block ----
    const size_t obase = (size_t)bid * ROW_ELEMS;
    const size_t gend  = obase + ROW_ELEMS;
    const size_t g0    = (obase + 3) & ~(size_t)3;   // first 16B-aligned element
    const size_t gbe   = gend & ~(size_t)3;          // end of aligned body
    const int head  = (int)(g0 - obase);             // 0..3
    const int tailn = (int)(gend - gbe);             // 0..3
    const int body  = (int)((gbe - g0) >> 2);        // float4 chunks (~4407)

    // scalar head + tail (<= 6 elements total)
    if (tid < 8) {
        int o = -1;
        if (tid < head) o = tid;
        else if (tid - head < tailn) o = (int)(gbe - obase) + (tid - head);
        if (o >= 0) {
            float sv, qv;
            compute_elem(lds, o, sv, qv);
            sw_out[obase + o] = sv;
            q_out[obase + o] = qv;
        }
    }

    // vectorized body: one float4 per thread per iteration; per-element
    // address math fully independent (ILP; r6's dependent walker regressed).
    // Plain stores (r7 A/B: nontemporal cost +33 us).
    for (int k = tid; k < body; k += 256) {
        size_t g = g0 + ((size_t)k << 2);
        int o = (int)(g - obase);
        float s0, s1, s2, s3, q0, q1, q2, q3;
        compute_elem(lds, o + 0, s0, q0);
        compute_elem(lds, o + 1, s1, q1);
        compute_elem(lds, o + 2, s2, q2);
        compute_elem(lds, o + 3, s3, q3);
        vf4 sv = {s0, s1, s2, s3};
        vf4 qv = {q0, q1, q2, q3};
        *reinterpret_cast<vf4*>(sw_out + g) = sv;
        *reinterpret_cast<vf4*>(q_out + g)  = qv;
    }

    // ---- stats: quad-of-lanes per window ----
    const int lane = tid & 63;
    const int wave = tid >> 6;
    const int j = (lane >> 2) + (wave << 4);   // 0..63; valid if < 61
    const int q = lane & 3;

    float sum = 0.0f, sumsq = 0.0f, mx = -1e30f, mn = 1e30f;
    if (j < NWIN) {
        const int e0 = 72 * q;
        const int lim = (q == 3) ? 73 : 72;    // 289 = 72*4 + 1
        const int jbase = j * STRIDE;
        for (int s = 0; s < lim; ++s) {
            int e = e0 + s;
            int u = e / MASK;                  // const-div
            int v = e - u * MASK;
            float xv = lds[swz(u * WW + jbase + v)];
            // shifted accumulation: var is shift-invariant; better conditioning.
            float xs = xv - 0.5f;
            sum += xs;
            sumsq += xs * xs;
            mx = fmaxf(mx, xv);
            mn = fminf(mn, xv);
        }
    }
    sum   += __shfl_xor(sum, 1, 64);
    sumsq += __shfl_xor(sumsq, 1, 64);
    mx = fmaxf(mx, __shfl_xor(mx, 1, 64));
    mn = fminf(mn, __shfl_xor(mn, 1, 64));
    sum   += __shfl_xor(sum, 2, 64);
    sumsq += __shfl_xor(sumsq, 2, 64);
    mx = fmaxf(mx, __shfl_xor(mx, 2, 64));
    mn = fminf(mn, __shfl_xor(mn, 2, 64));

    if (q == 0 && j < NWIN) {
        const float inv_n = 1.0f / (float)WIN_ELEMS;
        float ms = sum * inv_n;               // E[x] - 0.5
        float mean = 0.5f + ms;
        float var = fmaxf(sumsq * inv_n - ms * ms, 0.0f); // population std
        float sd = sqrtf(var);
        const float inv_std = 4.0f;  // 1 / G_STD
        size_t sb = (size_t)b * 12 * NN2 + (size_t)c * NN2 + (size_t)i * NWIN + j;
        s_out[sb + 0 * (size_t)CC * NN2] = (mx - 0.5f) * inv_std;
        s_out[sb + 1 * (size_t)CC * NN2] = sd * inv_std;
        s_out[sb + 2 * (size_t)CC * NN2] = (mx - mean) * inv_std;
        s_out[sb + 3 * (size_t)CC * NN2] = (mean - mn) * inv_std;
    }
}

extern "C" void kernel_launch(void* const* d_in, const int* in_sizes, int n_in,
                              void* d_out, int out_size, void* d_ws, size_t ws_size,
                              hipStream_t stream) {
    const float* x = (const float*)d_in[0];
    // d_in[1] = bins (linspace(0,1,65)) — semantics hardcoded (exact, see kernel)
    float* out = (float*)d_out;
    float* sw_out = out;
    float* s_out  = out + SW_SIZE;
    float* q_out  = out + SW_SIZE + S_SIZE;

    leafnet_kernel<<<NBLK, 256, 0, stream>>>(x, sw_out, s_out, q_out);
}

// Round 11
// 857.267 us; speedup vs baseline: 1.1835x; 1.0009x over previous
//
#include <hip/hip_runtime.h>

// Problem constants (fixed by setup_inputs)
#define BB 32
#define CC 3
#define HH 257
#define WW 257
#define MASK 17
#define STRIDE 4
#define NWIN 61           // (257-17)/4+1

constexpr int WIN_ELEMS = MASK * MASK;               // 289
constexpr int ROW_ELEMS = NWIN * WIN_ELEMS;          // 17629 contiguous sw elems per (b,c,i)
constexpr int BAND = MASK * WW;                      // 4369 contiguous x floats per block
constexpr long long SW_SIZE = (long long)BB * CC * NWIN * NWIN * WIN_ELEMS; // 103,235,424
constexpr long long S_SIZE  = (long long)BB * 4 * CC * NWIN * NWIN;         // 1,428,864
constexpr int NN2 = NWIN * NWIN;                     // 3721
constexpr int NBLK = BB * CC * NWIN;                 // 5856 = 8 * 732 (divisible by 8 XCDs)

typedef float vf4 __attribute__((ext_vector_type(4)));

// XOR bank swizzle: inject word bits [6:5] into bits [1:0].
// Main-loop lane-to-lane stride is +4..+8 words -> 8 banks/64 lanes = 8-way
// conflict unswizzled. Bits [6:5] flip every 8 lanes -> 32 lanes spread over
// all 32 banks -> ~2-way (free, m136). Pitch 257 (= WW): LDS band congruent
// to the contiguous global band -> float4 staging loads.
static __device__ __forceinline__ int swz(int w) {
    return w ^ ((w >> 5) & 3);
}

static __device__ __forceinline__ void compute_elem(
        const float* __restrict__ lds, int o, float& sv, float& qv) {
    int j = o / WIN_ELEMS;            // const-div -> magic mul
    int r = o - j * WIN_ELEMS;
    int u = r / MASK;
    int v = r - u * MASK;
    float xv = lds[swz(u * WW + j * STRIDE + v)];
    // digitize(x, linspace(0,1,65)) - 1 == clamp(floor(64*x), -1, 64); exact fp32
    int qi = (int)floorf(xv * 64.0f);
    qi = qi < -1 ? -1 : (qi > 64 ? 64 : qi);
    sv = xv;
    qv = (float)qi;
}

__global__ __launch_bounds__(256) void leafnet_kernel(
        const float* __restrict__ x,
        float* __restrict__ sw_out,
        float* __restrict__ s_out,
        float* __restrict__ q_out) {
    __shared__ float lds[BAND + 3];      // 4369 (+pad) floats = 17.49 KB, pitch 257

    // XCD-contiguous block remap (5856 = 8*732 -> clean bijection): neighbor
    // i-blocks (13/17 shared input rows) land on the same per-XCD L2.
    const int hw = blockIdx.x;
    const int bid = (hw & 7) * (NBLK / 8) + (hw >> 3);
    const int i = bid % NWIN;
    const int c = (bid / NWIN) % CC;
    const int b = bid / (NWIN * CC);
    const int tid = threadIdx.x;

    // ---- staging: float4 loads over the contiguous 4369-float band ----
    const size_t bandbase = ((size_t)(b * CC + c) * HH + (size_t)i * STRIDE) * WW;
    const float* xw = x + bandbase;
    const int mis  = (int)(bandbase & 3);          // base float index mod 4
    const int hcnt = (4 - mis) & 3;                // head words to align
    const int nb4  = (BAND - hcnt) >> 2;           // aligned float4 count (~1092)
    const int tcnt = (BAND - hcnt) & 3;            // tail words

    if (tid < 8) {                                  // head + tail (<= 6 words)
        int w = -1;
        if (tid < hcnt) w = tid;
        else if (tid - hcnt < tcnt) w = hcnt + (nb4 << 2) + (tid - hcnt);
        if (w >= 0) lds[swz(w)] = xw[w];
    }
    for (int k = tid; k < nb4; k += 256) {
        int w = hcnt + (k << 2);
        vf4 vv = *reinterpret_cast<const vf4*>(xw + w);
        lds[swz(w + 0)] = vv[0];
        lds[swz(w + 1)] = vv[1];
        lds[swz(w + 2)] = vv[2];
        lds[swz(w + 3)] = vv[3];
    }
    __syncthreads();

    // ---- sw + q: contiguous span [obase, obase+17629) per block ----
    const size_t obase = (size_t)bid * ROW_ELEMS;
    const size_t gend  = obase + ROW_ELEMS;
    const size_t g0    = (obase + 3) & ~(size_t)3;   // first 16B-aligned element
    const size_t gbe   = gend & ~(size_t)3;          // end of aligned body
    const int head  = (int)(g0 - obase);             // 0..3
    const int tailn = (int)(gend - gbe);             // 0..3
    const int body  = (int)((gbe - g0) >> 2);        // float4 chunks (~4407)
    const int nPair = body >> 1;                     // 8-elem chunks (~2203)

    // Main body: 8 elements (2 float4 pairs) per thread per iteration.
    // One div-pair per chunk; per-element INDEPENDENT carry adjustment
    // (v0<=16, e<=7 -> at most one v-carry and one u-carry; each element's
    // chain depends only on (v0,u0,j0,e) -> full ILP; r6's serial walker
    // regressed, this is its parallel form). 4 outstanding dwordx4 stores.
    // Bounds: max o+e = 17628 -> j <= 60 always; max LDS word 4368, swz
    // identity there -> in-bounds.
    for (int k = tid; k < nPair; k += 256) {
        size_t g = g0 + ((size_t)k << 3);
        int o = (int)(g - obase);
        int j0 = o / WIN_ELEMS;           // magic div, once per 8 elems
        int r = o - j0 * WIN_ELEMS;
        int u0 = r / MASK;
        int v0 = r - u0 * MASK;
        float sv[8], qv[8];
        #pragma unroll
        for (int e = 0; e < 8; ++e) {     // compile-time indices after unroll
            int v = v0 + e;
            int c1 = (v >= MASK) ? 1 : 0;
            v -= c1 ? MASK : 0;
            int u = u0 + c1;
            int c2 = (u >= MASK) ? 1 : 0;
            u -= c2 ? MASK : 0;
            int j = j0 + c2;
            float xv = lds[swz(u * WW + j * STRIDE + v)];
            int qi = (int)floorf(xv * 64.0f);
            qi = qi < -1 ? -1 : (qi > 64 ? 64 : qi);
            sv[e] = xv;
            qv[e] = (float)qi;
        }
        vf4 s0 = {sv[0], sv[1], sv[2], sv[3]};
        vf4 s1 = {sv[4], sv[5], sv[6], sv[7]};
        vf4 q0 = {qv[0], qv[1], qv[2], qv[3]};
        vf4 q1 = {qv[4], qv[5], qv[6], qv[7]};
        *reinterpret_cast<vf4*>(sw_out + g)     = s0;
        *(reinterpret_cast<vf4*>(sw_out + g)+1) = s1;
        *reinterpret_cast<vf4*>(q_out + g)      = q0;
        *(reinterpret_cast<vf4*>(q_out + g)+1)  = q1;
    }

    // Leftover float4 when body is odd (<= 1 chunk).
    for (int k = 2 * nPair + tid; k < body; k += 256) {
        size_t g = g0 + ((size_t)k << 2);
        int o = (int)(g - obase);
        float s0, s1, s2, s3, q0, q1, q2, q3;
        compute_elem(lds, o + 0, s0, q0);
        compute_elem(lds, o + 1, s1, q1);
        compute_elem(lds, o + 2, s2, q2);
        compute_elem(lds, o + 3, s3, q3);
        vf4 sv = {s0, s1, s2, s3};
        vf4 qv = {q0, q1, q2, q3};
        *reinterpret_cast<vf4*>(sw_out + g) = sv;
        *reinterpret_cast<vf4*>(q_out + g)  = qv;
    }

    // Scalar head + tail (<= 6 elements total).
    if (tid < 8) {
        int o = -1;
        if (tid < head) o = tid;
        else if (tid - head < tailn) o = (int)(gbe - obase) + (tid - head);
        if (o >= 0) {
            float sv, qv;
            compute_elem(lds, o, sv, qv);
            sw_out[obase + o] = sv;
            q_out[obase + o] = qv;
        }
    }

    // ---- stats: quad-of-lanes per window ----
    const int lane = tid & 63;
    const int wave = tid >> 6;
    const int j = (lane >> 2) + (wave << 4);   // 0..63; valid if < 61
    const int q = lane & 3;

    float sum = 0.0f, sumsq = 0.0f, mx = -1e30f, mn = 1e30f;
    if (j < NWIN) {
        const int e0 = 72 * q;
        const int lim = (q == 3) ? 73 : 72;    // 289 = 72*4 + 1
        const int jbase = j * STRIDE;
        for (int s = 0; s < lim; ++s) {
            int e = e0 + s;
            int u = e / MASK;                  // const-div
            int v = e - u * MASK;
            float xv = lds[swz(u * WW + jbase + v)];
            // shifted accumulation: var is shift-invariant; better conditioning.
            float xs = xv - 0.5f;
            sum += xs;
            sumsq += xs * xs;
            mx = fmaxf(mx, xv);
            mn = fminf(mn, xv);
        }
    }
    sum   += __shfl_xor(sum, 1, 64);
    sumsq += __shfl_xor(sumsq, 1, 64);
    mx = fmaxf(mx, __shfl_xor(mx, 1, 64));
    mn = fminf(mn, __shfl_xor(mn, 1, 64));
    sum   += __shfl_xor(sum, 2, 64);
    sumsq += __shfl_xor(sumsq, 2, 64);
    mx = fmaxf(mx, __shfl_xor(mx, 2, 64));
    mn = fminf(mn, __shfl_xor(mn, 2, 64));

    if (q == 0 && j < NWIN) {
        const float inv_n = 1.0f / (float)WIN_ELEMS;
        float ms = sum * inv_n;               // E[x] - 0.5
        float mean = 0.5f + ms;
        float var = fmaxf(sumsq * inv_n - ms * ms, 0.0f); // population std
        float sd = sqrtf(var);
        const float inv_std = 4.0f;  // 1 / G_STD
        size_t sb = (size_t)b * 12 * NN2 + (size_t)c * NN2 + (size_t)i * NWIN + j;
        s_out[sb + 0 * (size_t)CC * NN2] = (mx - 0.5f) * inv_std;
        s_out[sb + 1 * (size_t)CC * NN2] = sd * inv_std;
        s_out[sb + 2 * (size_t)CC * NN2] = (mx - mean) * inv_std;
        s_out[sb + 3 * (size_t)CC * NN2] = (mean - mn) * inv_std;
    }
}

extern "C" void kernel_launch(void* const* d_in, const int* in_sizes, int n_in,
                              void* d_out, int out_size, void* d_ws, size_t ws_size,
                              hipStream_t stream) {
    const float* x = (const float*)d_in[0];
    // d_in[1] = bins (linspace(0,1,65)) — semantics hardcoded (exact, see kernel)
    float* out = (float*)d_out;
    float* sw_out = out;
    float* s_out  = out + SW_SIZE;
    float* q_out  = out + SW_SIZE + S_SIZE;

    leafnet_kernel<<<NBLK, 256, 0, stream>>>(x, sw_out, s_out, q_out);
}